// Round 10
// baseline (429.782 us; speedup 1.0000x reference)
//
#include <hip/hip_runtime.h>
#include <hip/hip_bf16.h>

#define BATCH 8
#define NN 2048
#define FIN 256
#define FOUT 128
#define ROWS (BATCH*NN)
#define NP1 (NN+1)

// ---------------- K1: Wh = h @ W, W stored [F_in, F_out] (validated R3/R4/R5) ----------------
__global__ __launch_bounds__(128) void k_gemm(const float* __restrict__ h,
                                              const float* __restrict__ W,
                                              float* __restrict__ Wh){
  const int rbase = blockIdx.x * 8;
  const int o = threadIdx.x;
  float acc[8] = {};
  for (int k = 0; k < FIN; k++){
    float w = W[(size_t)k * FOUT + o];
    #pragma unroll
    for (int r = 0; r < 8; r++)
      acc[r] = fmaf(h[(size_t)(rbase + r) * FIN + k], w, acc[r]);
  }
  #pragma unroll
  for (int r = 0; r < 8; r++)
    Wh[(size_t)(rbase + r) * FOUT + o] = acc[r];
}

// ---------------- K1b: s_i = Wh.a_i, s_j = Wh.a_j (validated) ----------------
__global__ __launch_bounds__(128) void k_scores(const float* __restrict__ Wh,
                                                const float* __restrict__ ai,
                                                const float* __restrict__ aj,
                                                float* __restrict__ sI,
                                                float* __restrict__ sJ){
  __shared__ float r1[128], r2[128];
  const int row = blockIdx.x, t = threadIdx.x;
  float w = Wh[(size_t)row * FOUT + t];
  r1[t] = w * ai[t];
  r2[t] = w * aj[t];
  __syncthreads();
  for (int s = 64; s > 0; s >>= 1){
    if (t < s){ r1[t] += r1[t+s]; r2[t] += r2[t+s]; }
    __syncthreads();
  }
  if (t == 0){ sI[row] = r1[0]; sJ[row] = r2[0]; }
}

// ---------------- K2: brute-force rank "sort" of s_j per batch (validated R3/R4) ----------------
__global__ __launch_bounds__(256) void k_rank(const float* __restrict__ sJ,
                                              float* __restrict__ sortedS,
                                              int* __restrict__ perm,
                                              float* __restrict__ e1g,
                                              float* __restrict__ e2g){
  const int b = blockIdx.x >> 3;
  const int chunk = blockIdx.x & 7;
  __shared__ float v[NN];
  const float* s = sJ + b * NN;
  for (int i = threadIdx.x; i < NN; i += 256) v[i] = s[i];
  __syncthreads();
  const int j = chunk * 256 + threadIdx.x;
  const float x = v[j];
  int r = 0;
  for (int q = 0; q < NN; q++){
    float y = v[q];
    r += (y < x) || (y == x && q < j);   // strict total order -> permutation
  }
  sortedS[b * NN + r] = x;
  perm[b * NN + r] = j;
  e1g[b * NN + r] = expf(x);
  e2g[b * NN + r] = expf(0.01f * x);
}

// ---------------- K3: scalar inclusive prefix sums of e1, e2 (validated R3/R4) ----------------
__global__ __launch_bounds__(256) void k_sscan(const float* __restrict__ e1g,
                                               const float* __restrict__ e2g,
                                               float* __restrict__ aPre,
                                               float* __restrict__ bPre){
  const int b = blockIdx.x;
  const int t = threadIdx.x;
  __shared__ float p1[256], p2[256];
  __shared__ float x1[256], x2[256];
  const float* e1 = e1g + b * NN;
  const float* e2 = e2g + b * NN;
  float l1[8], l2[8];
  float s1 = 0.f, s2 = 0.f;
  #pragma unroll
  for (int q = 0; q < 8; q++){
    s1 += e1[t * 8 + q]; l1[q] = s1;
    s2 += e2[t * 8 + q]; l2[q] = s2;
  }
  p1[t] = s1; p2[t] = s2;
  __syncthreads();
  if (t == 0){
    float a = 0.f, c = 0.f;
    for (int q = 0; q < 256; q++){
      x1[q] = a; a += p1[q];
      x2[q] = c; c += p2[q];
    }
  }
  __syncthreads();
  const float b1 = x1[t], b2 = x2[t];
  float* aP = aPre + b * NP1;
  float* bP = bPre + b * NP1;
  #pragma unroll
  for (int q = 0; q < 8; q++){
    aP[1 + t * 8 + q] = b1 + l1[q];
    bP[1 + t * 8 + q] = b2 + l2[q];
  }
  if (t == 0){ aP[0] = 0.f; bP[0] = 0.f; }
}

// ---------------- K4: sequential vector prefix scans P1, P2 (validated R3/R4) ----------------
__global__ __launch_bounds__(64) void k_scan(const float* __restrict__ Wh,
                                             const int* __restrict__ perm,
                                             const float* __restrict__ e1g,
                                             const float* __restrict__ e2g,
                                             float* __restrict__ P1,
                                             float* __restrict__ P2){
  const int b = blockIdx.x >> 1;
  const int o = ((blockIdx.x & 1) << 6) + threadIdx.x;
  const int* pm = perm + b * NN;
  const float* e1 = e1g + b * NN;
  const float* e2 = e2g + b * NN;
  const float* whb = Wh + (size_t)b * NN * FOUT;
  float* p1 = P1 + (size_t)b * NP1 * FOUT + o;
  float* p2 = P2 + (size_t)b * NP1 * FOUT + o;
  p1[0] = 0.f; p2[0] = 0.f;
  float acc1 = 0.f, acc2 = 0.f;
  #pragma unroll 4
  for (int r = 0; r < NN; r++){
    float w = whb[(size_t)pm[r] * FOUT + o];
    acc1 = fmaf(e1[r], w, acc1);
    acc2 = fmaf(e2[r], w, acc2);
    p1[(size_t)(r + 1) * FOUT] = acc1;
    p2[(size_t)(r + 1) * FOUT] = acc2;
  }
}

// ---------------- K5: per-row combine — FP32 STORE (the one semantic fix) ----------------
__global__ __launch_bounds__(128) void k_out(const float* __restrict__ sI,
                                             const float* __restrict__ sortedS,
                                             const float* __restrict__ aPre,
                                             const float* __restrict__ bPre,
                                             const float* __restrict__ P1,
                                             const float* __restrict__ P2,
                                             float* __restrict__ out){
  const int row = blockIdx.x;
  const int b = row >> 11;
  const float s = sI[row];
  const float key = -s;
  const float* ss = sortedS + b * NN;
  int lo = 0, hi = NN;
  while (lo < hi){
    int mid = (lo + hi) >> 1;
    if (ss[mid] <= key) lo = mid + 1; else hi = mid;
  }
  const int k = lo;                         // #{ s_j <= -s_i } -> 0.01-side
  const float w1 = expf(s), w2 = expf(0.01f * s);
  const float aT = aPre[b * NP1 + NN];
  const float ak = aPre[b * NP1 + k];
  const float bk = bPre[b * NP1 + k];
  const float inv = 1.0f / (w1 * (aT - ak) + w2 * bk);
  const int o = threadIdx.x;
  const float* p1k = P1 + ((size_t)b * NP1 + k) * FOUT;
  const float* p1T = P1 + ((size_t)b * NP1 + NN) * FOUT;
  const float* p2k = P2 + ((size_t)b * NP1 + k) * FOUT;
  float num = w1 * (p1T[o] - p1k[o]) + w2 * p2k[o];
  out[(size_t)row * FOUT + o] = num * inv;   // fp32 output — reference dtype
}

extern "C" void kernel_launch(void* const* d_in, const int* in_sizes, int n_in,
                              void* d_out, int out_size, void* d_ws, size_t ws_size,
                              hipStream_t stream){
  const float* h  = (const float*)d_in[0];
  const float* W  = (const float*)d_in[1];
  const float* ai = (const float*)d_in[2];
  const float* aj = (const float*)d_in[3];
  float* out = (float*)d_out;               // fp32: reference's output dtype

  char* ws = (char*)d_ws;
  size_t off = 0;
  auto alloc = [&](size_t bytes) -> void* {
    void* p = ws + off;
    off += (bytes + 255) & ~(size_t)255;
    return p;
  };
  float* Wh      = (float*)alloc((size_t)ROWS * FOUT * 4);        // 8 MB
  float* sI      = (float*)alloc((size_t)ROWS * 4);
  float* sJ      = (float*)alloc((size_t)ROWS * 4);
  float* sortedS = (float*)alloc((size_t)BATCH * NN * 4);
  int*   perm    = (int*)  alloc((size_t)BATCH * NN * 4);
  float* e1      = (float*)alloc((size_t)BATCH * NN * 4);
  float* e2      = (float*)alloc((size_t)BATCH * NN * 4);
  float* aPre    = (float*)alloc((size_t)BATCH * NP1 * 4);
  float* bPre    = (float*)alloc((size_t)BATCH * NP1 * 4);
  float* P1      = (float*)alloc((size_t)BATCH * NP1 * FOUT * 4); // 8.4 MB
  float* P2      = (float*)alloc((size_t)BATCH * NP1 * FOUT * 4); // 8.4 MB

  k_gemm  <<<ROWS / 8, 128, 0, stream>>>(h, W, Wh);
  k_scores<<<ROWS, 128, 0, stream>>>(Wh, ai, aj, sI, sJ);
  k_rank  <<<BATCH * 8, 256, 0, stream>>>(sJ, sortedS, perm, e1, e2);
  k_sscan <<<BATCH, 256, 0, stream>>>(e1, e2, aPre, bPre);
  k_scan  <<<BATCH * 2, 64, 0, stream>>>(Wh, perm, e1, e2, P1, P2);
  k_out   <<<ROWS, 128, 0, stream>>>(sI, sortedS, aPre, bPre, P1, P2, out);
}

// Round 11
// 230.948 us; speedup vs baseline: 1.8610x; 1.8610x over previous
//
#include <hip/hip_runtime.h>
#include <hip/hip_bf16.h>

#define BATCH 8
#define NN 2048
#define FIN 256
#define FOUT 128
#define ROWS (BATCH*NN)
#define NP1 (NN+1)
#define CHK 64           // chunks per batch
#define CLEN (NN/CHK)    // 32 rows per chunk

// ---------------- K1: Wh = h @ W, W stored [F_in, F_out] (green R10) ----------------
__global__ __launch_bounds__(128) void k_gemm(const float* __restrict__ h,
                                              const float* __restrict__ W,
                                              float* __restrict__ Wh){
  const int rbase = blockIdx.x * 8;
  const int o = threadIdx.x;
  float acc[8] = {};
  for (int k = 0; k < FIN; k++){
    float w = W[(size_t)k * FOUT + o];
    #pragma unroll
    for (int r = 0; r < 8; r++)
      acc[r] = fmaf(h[(size_t)(rbase + r) * FIN + k], w, acc[r]);
  }
  #pragma unroll
  for (int r = 0; r < 8; r++)
    Wh[(size_t)(rbase + r) * FOUT + o] = acc[r];
}

// ---------------- K1b: s_i = Wh.a_i, s_j = Wh.a_j (green R10) ----------------
__global__ __launch_bounds__(128) void k_scores(const float* __restrict__ Wh,
                                                const float* __restrict__ ai,
                                                const float* __restrict__ aj,
                                                float* __restrict__ sI,
                                                float* __restrict__ sJ){
  __shared__ float r1[128], r2[128];
  const int row = blockIdx.x, t = threadIdx.x;
  float w = Wh[(size_t)row * FOUT + t];
  r1[t] = w * ai[t];
  r2[t] = w * aj[t];
  __syncthreads();
  for (int s = 64; s > 0; s >>= 1){
    if (t < s){ r1[t] += r1[t+s]; r2[t] += r2[t+s]; }
    __syncthreads();
  }
  if (t == 0){ sI[row] = r1[0]; sJ[row] = r2[0]; }
}

// ---------------- K2: brute-force rank "sort" of s_j per batch (green R10) ----------------
__global__ __launch_bounds__(256) void k_rank(const float* __restrict__ sJ,
                                              float* __restrict__ sortedS,
                                              int* __restrict__ perm,
                                              float* __restrict__ e1g,
                                              float* __restrict__ e2g){
  const int b = blockIdx.x >> 3;
  const int chunk = blockIdx.x & 7;
  __shared__ float v[NN];
  const float* s = sJ + b * NN;
  for (int i = threadIdx.x; i < NN; i += 256) v[i] = s[i];
  __syncthreads();
  const int j = chunk * 256 + threadIdx.x;
  const float x = v[j];
  int r = 0;
  for (int q = 0; q < NN; q++){
    float y = v[q];
    r += (y < x) || (y == x && q < j);   // strict total order -> permutation
  }
  sortedS[b * NN + r] = x;
  perm[b * NN + r] = j;
  e1g[b * NN + r] = expf(x);
  e2g[b * NN + r] = expf(0.01f * x);
}

// ---------------- K3: scalar inclusive prefix sums of e1, e2 (green R10) ----------------
__global__ __launch_bounds__(256) void k_sscan(const float* __restrict__ e1g,
                                               const float* __restrict__ e2g,
                                               float* __restrict__ aPre,
                                               float* __restrict__ bPre){
  const int b = blockIdx.x;
  const int t = threadIdx.x;
  __shared__ float p1[256], p2[256];
  __shared__ float x1[256], x2[256];
  const float* e1 = e1g + b * NN;
  const float* e2 = e2g + b * NN;
  float l1[8], l2[8];
  float s1 = 0.f, s2 = 0.f;
  #pragma unroll
  for (int q = 0; q < 8; q++){
    s1 += e1[t * 8 + q]; l1[q] = s1;
    s2 += e2[t * 8 + q]; l2[q] = s2;
  }
  p1[t] = s1; p2[t] = s2;
  __syncthreads();
  if (t == 0){
    float a = 0.f, c = 0.f;
    for (int q = 0; q < 256; q++){
      x1[q] = a; a += p1[q];
      x2[q] = c; c += p2[q];
    }
  }
  __syncthreads();
  const float b1 = x1[t], b2 = x2[t];
  float* aP = aPre + b * NP1;
  float* bP = bPre + b * NP1;
  #pragma unroll
  for (int q = 0; q < 8; q++){
    aP[1 + t * 8 + q] = b1 + l1[q];
    bP[1 + t * 8 + q] = b2 + l2[q];
  }
  if (t == 0){ aP[0] = 0.f; bP[0] = 0.f; }
}

// ---------------- K4a: per-chunk vector totals (parallel scan, pass 1) ----------------
__global__ __launch_bounds__(128) void k_csum(const float* __restrict__ Wh,
                                              const int* __restrict__ perm,
                                              const float* __restrict__ e1g,
                                              const float* __restrict__ e2g,
                                              float* __restrict__ T1,
                                              float* __restrict__ T2){
  const int b = blockIdx.x >> 6;           // CHK = 64
  const int c = blockIdx.x & 63;
  const int o = threadIdx.x;
  const int* pm = perm + b * NN + c * CLEN;
  const float* e1 = e1g + b * NN + c * CLEN;
  const float* e2 = e2g + b * NN + c * CLEN;
  const float* whb = Wh + (size_t)b * NN * FOUT;
  float t1 = 0.f, t2 = 0.f;
  #pragma unroll 8
  for (int r = 0; r < CLEN; r++){
    float w = whb[(size_t)pm[r] * FOUT + o];
    t1 = fmaf(e1[r], w, t1);
    t2 = fmaf(e2[r], w, t2);
  }
  T1[(size_t)(b * CHK + c) * FOUT + o] = t1;
  T2[(size_t)(b * CHK + c) * FOUT + o] = t2;
}

// ---------------- K4b: chunk-offset + local scan (parallel scan, pass 2) ----------------
__global__ __launch_bounds__(128) void k_scan2(const float* __restrict__ Wh,
                                               const int* __restrict__ perm,
                                               const float* __restrict__ e1g,
                                               const float* __restrict__ e2g,
                                               const float* __restrict__ T1,
                                               const float* __restrict__ T2,
                                               float* __restrict__ P1,
                                               float* __restrict__ P2){
  const int b = blockIdx.x >> 6;
  const int c = blockIdx.x & 63;
  const int o = threadIdx.x;
  float acc1 = 0.f, acc2 = 0.f;
  for (int q = 0; q < c; q++){            // wave-uniform trip count, indep loads
    acc1 += T1[(size_t)(b * CHK + q) * FOUT + o];
    acc2 += T2[(size_t)(b * CHK + q) * FOUT + o];
  }
  const int g0 = c * CLEN;
  const int* pm = perm + b * NN + g0;
  const float* e1 = e1g + b * NN + g0;
  const float* e2 = e2g + b * NN + g0;
  const float* whb = Wh + (size_t)b * NN * FOUT;
  float* p1 = P1 + (size_t)b * NP1 * FOUT + o;
  float* p2 = P2 + (size_t)b * NP1 * FOUT + o;
  if (c == 0){ p1[0] = 0.f; p2[0] = 0.f; }
  #pragma unroll 4
  for (int r = 0; r < CLEN; r++){
    float w = whb[(size_t)pm[r] * FOUT + o];
    acc1 = fmaf(e1[r], w, acc1);
    acc2 = fmaf(e2[r], w, acc2);
    p1[(size_t)(g0 + r + 1) * FOUT] = acc1;
    p2[(size_t)(g0 + r + 1) * FOUT] = acc2;
  }
}

// ---------------- K5: per-row combine, fp32 store (green R10) ----------------
__global__ __launch_bounds__(128) void k_out(const float* __restrict__ sI,
                                             const float* __restrict__ sortedS,
                                             const float* __restrict__ aPre,
                                             const float* __restrict__ bPre,
                                             const float* __restrict__ P1,
                                             const float* __restrict__ P2,
                                             float* __restrict__ out){
  const int row = blockIdx.x;
  const int b = row >> 11;
  const float s = sI[row];
  const float key = -s;
  const float* ss = sortedS + b * NN;
  int lo = 0, hi = NN;
  while (lo < hi){
    int mid = (lo + hi) >> 1;
    if (ss[mid] <= key) lo = mid + 1; else hi = mid;
  }
  const int k = lo;                         // #{ s_j <= -s_i } -> 0.01-side
  const float w1 = expf(s), w2 = expf(0.01f * s);
  const float aT = aPre[b * NP1 + NN];
  const float ak = aPre[b * NP1 + k];
  const float bk = bPre[b * NP1 + k];
  const float inv = 1.0f / (w1 * (aT - ak) + w2 * bk);
  const int o = threadIdx.x;
  const float* p1k = P1 + ((size_t)b * NP1 + k) * FOUT;
  const float* p1T = P1 + ((size_t)b * NP1 + NN) * FOUT;
  const float* p2k = P2 + ((size_t)b * NP1 + k) * FOUT;
  float num = w1 * (p1T[o] - p1k[o]) + w2 * p2k[o];
  out[(size_t)row * FOUT + o] = num * inv;
}

extern "C" void kernel_launch(void* const* d_in, const int* in_sizes, int n_in,
                              void* d_out, int out_size, void* d_ws, size_t ws_size,
                              hipStream_t stream){
  const float* h  = (const float*)d_in[0];
  const float* W  = (const float*)d_in[1];
  const float* ai = (const float*)d_in[2];
  const float* aj = (const float*)d_in[3];
  float* out = (float*)d_out;

  char* ws = (char*)d_ws;
  size_t off = 0;
  auto alloc = [&](size_t bytes) -> void* {
    void* p = ws + off;
    off += (bytes + 255) & ~(size_t)255;
    return p;
  };
  float* Wh      = (float*)alloc((size_t)ROWS * FOUT * 4);        // 8 MB
  float* sI      = (float*)alloc((size_t)ROWS * 4);
  float* sJ      = (float*)alloc((size_t)ROWS * 4);
  float* sortedS = (float*)alloc((size_t)BATCH * NN * 4);
  int*   perm    = (int*)  alloc((size_t)BATCH * NN * 4);
  float* e1      = (float*)alloc((size_t)BATCH * NN * 4);
  float* e2      = (float*)alloc((size_t)BATCH * NN * 4);
  float* aPre    = (float*)alloc((size_t)BATCH * NP1 * 4);
  float* bPre    = (float*)alloc((size_t)BATCH * NP1 * 4);
  float* T1      = (float*)alloc((size_t)BATCH * CHK * FOUT * 4); // 256 KB
  float* T2      = (float*)alloc((size_t)BATCH * CHK * FOUT * 4); // 256 KB
  float* P1      = (float*)alloc((size_t)BATCH * NP1 * FOUT * 4); // 8.4 MB
  float* P2      = (float*)alloc((size_t)BATCH * NP1 * FOUT * 4); // 8.4 MB

  k_gemm  <<<ROWS / 8, 128, 0, stream>>>(h, W, Wh);
  k_scores<<<ROWS, 128, 0, stream>>>(Wh, ai, aj, sI, sJ);
  k_rank  <<<BATCH * 8, 256, 0, stream>>>(sJ, sortedS, perm, e1, e2);
  k_sscan <<<BATCH, 256, 0, stream>>>(e1, e2, aPre, bPre);
  k_csum  <<<BATCH * CHK, 128, 0, stream>>>(Wh, perm, e1, e2, T1, T2);
  k_scan2 <<<BATCH * CHK, 128, 0, stream>>>(Wh, perm, e1, e2, T1, T2, P1, P2);
  k_out   <<<ROWS, 128, 0, stream>>>(sI, sortedS, aPre, bPre, P1, P2, out);
}

// Round 12
// 188.959 us; speedup vs baseline: 2.2745x; 1.2222x over previous
//
#include <hip/hip_runtime.h>
#include <hip/hip_bf16.h>

#define BATCH 8
#define NN 2048
#define FIN 256
#define FOUT 128
#define ROWS (BATCH*NN)
#define NP1 (NN+1)
#define CHK 64           // chunks per batch
#define CLEN (NN/CHK)    // 32 rows per chunk

// ---------------- K1: tiled Wh = h @ W + fused s_i/s_j ----------------
// 32x128 C-tile, BK=32, 256 threads, 4x4 acc/thread.
__global__ __launch_bounds__(256) void k_gemm(const float* __restrict__ h,
                                              const float* __restrict__ W,
                                              const float* __restrict__ ai,
                                              const float* __restrict__ aj,
                                              float* __restrict__ Wh,
                                              float* __restrict__ sI,
                                              float* __restrict__ sJ){
  __shared__ float As[32][36];    // [m][k], pad 36 keeps float4 stores aligned
  __shared__ float Bs[32][128];   // [k][o]
  const int t = threadIdx.x;
  const int rbase = blockIdx.x * 32;
  const int tx = t & 31, ty = t >> 5;
  const int o0 = tx * 4, m0 = ty * 4;
  const int ar = t >> 3, ak = (t & 7) * 4;
  float acc[4][4] = {};
  for (int k0 = 0; k0 < FIN; k0 += 32){
    *(float4*)&As[ar][ak] = *(const float4*)&h[(size_t)(rbase + ar) * FIN + k0 + ak];
    #pragma unroll
    for (int u = 0; u < 4; u++){
      int idx = t + u * 256;
      int kk = idx >> 5, q = idx & 31;
      *(float4*)&Bs[kk][q * 4] = *(const float4*)&W[(size_t)(k0 + kk) * FOUT + q * 4];
    }
    __syncthreads();
    #pragma unroll
    for (int kk = 0; kk < 32; kk++){
      float a0 = As[m0 + 0][kk], a1 = As[m0 + 1][kk];
      float a2 = As[m0 + 2][kk], a3 = As[m0 + 3][kk];
      float4 bv = *(const float4*)&Bs[kk][o0];
      acc[0][0] = fmaf(a0, bv.x, acc[0][0]); acc[0][1] = fmaf(a0, bv.y, acc[0][1]);
      acc[0][2] = fmaf(a0, bv.z, acc[0][2]); acc[0][3] = fmaf(a0, bv.w, acc[0][3]);
      acc[1][0] = fmaf(a1, bv.x, acc[1][0]); acc[1][1] = fmaf(a1, bv.y, acc[1][1]);
      acc[1][2] = fmaf(a1, bv.z, acc[1][2]); acc[1][3] = fmaf(a1, bv.w, acc[1][3]);
      acc[2][0] = fmaf(a2, bv.x, acc[2][0]); acc[2][1] = fmaf(a2, bv.y, acc[2][1]);
      acc[2][2] = fmaf(a2, bv.z, acc[2][2]); acc[2][3] = fmaf(a2, bv.w, acc[2][3]);
      acc[3][0] = fmaf(a3, bv.x, acc[3][0]); acc[3][1] = fmaf(a3, bv.y, acc[3][1]);
      acc[3][2] = fmaf(a3, bv.z, acc[3][2]); acc[3][3] = fmaf(a3, bv.w, acc[3][3]);
    }
    __syncthreads();
  }
  const float4 av = *(const float4*)&ai[o0];
  const float4 bjv = *(const float4*)&aj[o0];
  #pragma unroll
  for (int i = 0; i < 4; i++){
    float4 v = {acc[i][0], acc[i][1], acc[i][2], acc[i][3]};
    *(float4*)&Wh[(size_t)(rbase + m0 + i) * FOUT + o0] = v;
    float pi = v.x * av.x + v.y * av.y + v.z * av.z + v.w * av.w;
    float pj = v.x * bjv.x + v.y * bjv.y + v.z * bjv.z + v.w * bjv.w;
    #pragma unroll
    for (int m = 1; m < 32; m <<= 1){   // reduce across tx within each 32-lane half
      pi += __shfl_xor(pi, m);
      pj += __shfl_xor(pj, m);
    }
    if (tx == 0){
      sI[rbase + m0 + i] = pi;
      sJ[rbase + m0 + i] = pj;
    }
  }
}

// ---------------- K2: rank "sort" of s_j per batch, float4 inner loop ----------------
__global__ __launch_bounds__(256) void k_rank(const float* __restrict__ sJ,
                                              float* __restrict__ sortedS,
                                              int* __restrict__ perm,
                                              float* __restrict__ e1g,
                                              float* __restrict__ e2g){
  const int b = blockIdx.x >> 3;
  const int chunk = blockIdx.x & 7;
  __shared__ float v[NN];
  const float* s = sJ + b * NN;
  for (int i = threadIdx.x; i < NN; i += 256) v[i] = s[i];
  __syncthreads();
  const int j = chunk * 256 + threadIdx.x;
  const float x = v[j];
  int r = 0;
  #pragma unroll 4
  for (int q4 = 0; q4 < NN / 4; q4++){
    const int q = q4 * 4;
    float4 y = *(const float4*)&v[q];
    r += (y.x < x) || (y.x == x && (q + 0) < j);
    r += (y.y < x) || (y.y == x && (q + 1) < j);
    r += (y.z < x) || (y.z == x && (q + 2) < j);
    r += (y.w < x) || (y.w == x && (q + 3) < j);
  }
  sortedS[b * NN + r] = x;
  perm[b * NN + r] = j;
  e1g[b * NN + r] = expf(x);
  e2g[b * NN + r] = expf(0.01f * x);
}

// ---------------- K3: scalar inclusive prefix sums of e1, e2 (green) ----------------
__global__ __launch_bounds__(256) void k_sscan(const float* __restrict__ e1g,
                                               const float* __restrict__ e2g,
                                               float* __restrict__ aPre,
                                               float* __restrict__ bPre){
  const int b = blockIdx.x;
  const int t = threadIdx.x;
  __shared__ float p1[256], p2[256];
  __shared__ float x1[256], x2[256];
  const float* e1 = e1g + b * NN;
  const float* e2 = e2g + b * NN;
  float l1[8], l2[8];
  float s1 = 0.f, s2 = 0.f;
  #pragma unroll
  for (int q = 0; q < 8; q++){
    s1 += e1[t * 8 + q]; l1[q] = s1;
    s2 += e2[t * 8 + q]; l2[q] = s2;
  }
  p1[t] = s1; p2[t] = s2;
  __syncthreads();
  if (t == 0){
    float a = 0.f, c = 0.f;
    for (int q = 0; q < 256; q++){
      x1[q] = a; a += p1[q];
      x2[q] = c; c += p2[q];
    }
  }
  __syncthreads();
  const float b1 = x1[t], b2 = x2[t];
  float* aP = aPre + b * NP1;
  float* bP = bPre + b * NP1;
  #pragma unroll
  for (int q = 0; q < 8; q++){
    aP[1 + t * 8 + q] = b1 + l1[q];
    bP[1 + t * 8 + q] = b2 + l2[q];
  }
  if (t == 0){ aP[0] = 0.f; bP[0] = 0.f; }
}

// ---------------- K4a: per-chunk vector totals (green) ----------------
__global__ __launch_bounds__(128) void k_csum(const float* __restrict__ Wh,
                                              const int* __restrict__ perm,
                                              const float* __restrict__ e1g,
                                              const float* __restrict__ e2g,
                                              float* __restrict__ T1,
                                              float* __restrict__ T2){
  const int b = blockIdx.x >> 6;
  const int c = blockIdx.x & 63;
  const int o = threadIdx.x;
  const int* pm = perm + b * NN + c * CLEN;
  const float* e1 = e1g + b * NN + c * CLEN;
  const float* e2 = e2g + b * NN + c * CLEN;
  const float* whb = Wh + (size_t)b * NN * FOUT;
  float t1 = 0.f, t2 = 0.f;
  #pragma unroll 8
  for (int r = 0; r < CLEN; r++){
    float w = whb[(size_t)pm[r] * FOUT + o];
    t1 = fmaf(e1[r], w, t1);
    t2 = fmaf(e2[r], w, t2);
  }
  T1[(size_t)(b * CHK + c) * FOUT + o] = t1;
  T2[(size_t)(b * CHK + c) * FOUT + o] = t2;
}

// ---------------- K4b: chunk-offset + local scan (green) ----------------
__global__ __launch_bounds__(128) void k_scan2(const float* __restrict__ Wh,
                                               const int* __restrict__ perm,
                                               const float* __restrict__ e1g,
                                               const float* __restrict__ e2g,
                                               const float* __restrict__ T1,
                                               const float* __restrict__ T2,
                                               float* __restrict__ P1,
                                               float* __restrict__ P2){
  const int b = blockIdx.x >> 6;
  const int c = blockIdx.x & 63;
  const int o = threadIdx.x;
  float acc1 = 0.f, acc2 = 0.f;
  for (int q = 0; q < c; q++){
    acc1 += T1[(size_t)(b * CHK + q) * FOUT + o];
    acc2 += T2[(size_t)(b * CHK + q) * FOUT + o];
  }
  const int g0 = c * CLEN;
  const int* pm = perm + b * NN + g0;
  const float* e1 = e1g + b * NN + g0;
  const float* e2 = e2g + b * NN + g0;
  const float* whb = Wh + (size_t)b * NN * FOUT;
  float* p1 = P1 + (size_t)b * NP1 * FOUT + o;
  float* p2 = P2 + (size_t)b * NP1 * FOUT + o;
  if (c == 0){ p1[0] = 0.f; p2[0] = 0.f; }
  #pragma unroll 4
  for (int r = 0; r < CLEN; r++){
    float w = whb[(size_t)pm[r] * FOUT + o];
    acc1 = fmaf(e1[r], w, acc1);
    acc2 = fmaf(e2[r], w, acc2);
    p1[(size_t)(g0 + r + 1) * FOUT] = acc1;
    p2[(size_t)(g0 + r + 1) * FOUT] = acc2;
  }
}

// ---------------- K5: per-row combine, fp32 store (green) ----------------
__global__ __launch_bounds__(128) void k_out(const float* __restrict__ sI,
                                             const float* __restrict__ sortedS,
                                             const float* __restrict__ aPre,
                                             const float* __restrict__ bPre,
                                             const float* __restrict__ P1,
                                             const float* __restrict__ P2,
                                             float* __restrict__ out){
  const int row = blockIdx.x;
  const int b = row >> 11;
  const float s = sI[row];
  const float key = -s;
  const float* ss = sortedS + b * NN;
  int lo = 0, hi = NN;
  while (lo < hi){
    int mid = (lo + hi) >> 1;
    if (ss[mid] <= key) lo = mid + 1; else hi = mid;
  }
  const int k = lo;
  const float w1 = expf(s), w2 = expf(0.01f * s);
  const float aT = aPre[b * NP1 + NN];
  const float ak = aPre[b * NP1 + k];
  const float bk = bPre[b * NP1 + k];
  const float inv = 1.0f / (w1 * (aT - ak) + w2 * bk);
  const int o = threadIdx.x;
  const float* p1k = P1 + ((size_t)b * NP1 + k) * FOUT;
  const float* p1T = P1 + ((size_t)b * NP1 + NN) * FOUT;
  const float* p2k = P2 + ((size_t)b * NP1 + k) * FOUT;
  float num = w1 * (p1T[o] - p1k[o]) + w2 * p2k[o];
  out[(size_t)row * FOUT + o] = num * inv;
}

extern "C" void kernel_launch(void* const* d_in, const int* in_sizes, int n_in,
                              void* d_out, int out_size, void* d_ws, size_t ws_size,
                              hipStream_t stream){
  const float* h  = (const float*)d_in[0];
  const float* W  = (const float*)d_in[1];
  const float* ai = (const float*)d_in[2];
  const float* aj = (const float*)d_in[3];
  float* out = (float*)d_out;

  char* ws = (char*)d_ws;
  size_t off = 0;
  auto alloc = [&](size_t bytes) -> void* {
    void* p = ws + off;
    off += (bytes + 255) & ~(size_t)255;
    return p;
  };
  float* Wh      = (float*)alloc((size_t)ROWS * FOUT * 4);        // 8 MB
  float* sI      = (float*)alloc((size_t)ROWS * 4);
  float* sJ      = (float*)alloc((size_t)ROWS * 4);
  float* sortedS = (float*)alloc((size_t)BATCH * NN * 4);
  int*   perm    = (int*)  alloc((size_t)BATCH * NN * 4);
  float* e1      = (float*)alloc((size_t)BATCH * NN * 4);
  float* e2      = (float*)alloc((size_t)BATCH * NN * 4);
  float* aPre    = (float*)alloc((size_t)BATCH * NP1 * 4);
  float* bPre    = (float*)alloc((size_t)BATCH * NP1 * 4);
  float* T1      = (float*)alloc((size_t)BATCH * CHK * FOUT * 4); // 256 KB
  float* T2      = (float*)alloc((size_t)BATCH * CHK * FOUT * 4); // 256 KB
  float* P1      = (float*)alloc((size_t)BATCH * NP1 * FOUT * 4); // 8.4 MB
  float* P2      = (float*)alloc((size_t)BATCH * NP1 * FOUT * 4); // 8.4 MB

  k_gemm  <<<ROWS / 32, 256, 0, stream>>>(h, W, ai, aj, Wh, sI, sJ);
  k_rank  <<<BATCH * 8, 256, 0, stream>>>(sJ, sortedS, perm, e1, e2);
  k_sscan <<<BATCH, 256, 0, stream>>>(e1, e2, aPre, bPre);
  k_csum  <<<BATCH * CHK, 128, 0, stream>>>(Wh, perm, e1, e2, T1, T2);
  k_scan2 <<<BATCH * CHK, 128, 0, stream>>>(Wh, perm, e1, e2, T1, T2, P1, P2);
  k_out   <<<ROWS, 128, 0, stream>>>(sI, sortedS, aPre, bPre, P1, P2, out);
}

// Round 13
// 146.820 us; speedup vs baseline: 2.9273x; 1.2870x over previous
//
#include <hip/hip_runtime.h>
#include <hip/hip_bf16.h>

#define BATCH 8
#define NN 2048
#define FIN 256
#define FOUT 128
#define ROWS (BATCH*NN)
#define NP1 (NN+1)
#define CHK 64           // chunks per batch (vector scan)
#define CLEN (NN/CHK)    // 32 rows per chunk

// ---------------- K1: tiled Wh = h @ W + fused s_i/s_j (green R12) ----------------
__global__ __launch_bounds__(256) void k_gemm(const float* __restrict__ h,
                                              const float* __restrict__ W,
                                              const float* __restrict__ ai,
                                              const float* __restrict__ aj,
                                              float* __restrict__ Wh,
                                              float* __restrict__ sI,
                                              float* __restrict__ sJ){
  __shared__ float As[32][36];
  __shared__ float Bs[32][128];
  const int t = threadIdx.x;
  const int rbase = blockIdx.x * 32;
  const int tx = t & 31, ty = t >> 5;
  const int o0 = tx * 4, m0 = ty * 4;
  const int ar = t >> 3, ak = (t & 7) * 4;
  float acc[4][4] = {};
  for (int k0 = 0; k0 < FIN; k0 += 32){
    *(float4*)&As[ar][ak] = *(const float4*)&h[(size_t)(rbase + ar) * FIN + k0 + ak];
    #pragma unroll
    for (int u = 0; u < 4; u++){
      int idx = t + u * 256;
      int kk = idx >> 5, q = idx & 31;
      *(float4*)&Bs[kk][q * 4] = *(const float4*)&W[(size_t)(k0 + kk) * FOUT + q * 4];
    }
    __syncthreads();
    #pragma unroll
    for (int kk = 0; kk < 32; kk++){
      float a0 = As[m0 + 0][kk], a1 = As[m0 + 1][kk];
      float a2 = As[m0 + 2][kk], a3 = As[m0 + 3][kk];
      float4 bv = *(const float4*)&Bs[kk][o0];
      acc[0][0] = fmaf(a0, bv.x, acc[0][0]); acc[0][1] = fmaf(a0, bv.y, acc[0][1]);
      acc[0][2] = fmaf(a0, bv.z, acc[0][2]); acc[0][3] = fmaf(a0, bv.w, acc[0][3]);
      acc[1][0] = fmaf(a1, bv.x, acc[1][0]); acc[1][1] = fmaf(a1, bv.y, acc[1][1]);
      acc[1][2] = fmaf(a1, bv.z, acc[1][2]); acc[1][3] = fmaf(a1, bv.w, acc[1][3]);
      acc[2][0] = fmaf(a2, bv.x, acc[2][0]); acc[2][1] = fmaf(a2, bv.y, acc[2][1]);
      acc[2][2] = fmaf(a2, bv.z, acc[2][2]); acc[2][3] = fmaf(a2, bv.w, acc[2][3]);
      acc[3][0] = fmaf(a3, bv.x, acc[3][0]); acc[3][1] = fmaf(a3, bv.y, acc[3][1]);
      acc[3][2] = fmaf(a3, bv.z, acc[3][2]); acc[3][3] = fmaf(a3, bv.w, acc[3][3]);
    }
    __syncthreads();
  }
  const float4 av = *(const float4*)&ai[o0];
  const float4 bjv = *(const float4*)&aj[o0];
  #pragma unroll
  for (int i = 0; i < 4; i++){
    float4 v = {acc[i][0], acc[i][1], acc[i][2], acc[i][3]};
    *(float4*)&Wh[(size_t)(rbase + m0 + i) * FOUT + o0] = v;
    float pi = v.x * av.x + v.y * av.y + v.z * av.z + v.w * av.w;
    float pj = v.x * bjv.x + v.y * bjv.y + v.z * bjv.z + v.w * bjv.w;
    #pragma unroll
    for (int m = 1; m < 32; m <<= 1){
      pi += __shfl_xor(pi, m);
      pj += __shfl_xor(pj, m);
    }
    if (tx == 0){
      sI[rbase + m0 + i] = pi;
      sJ[rbase + m0 + i] = pj;
    }
  }
}

// ---------------- K2a: partial rank counts, q-parallel ----------------
// grid = BATCH * 8(qc) * 8(jc); block counts 256 j's against one 256-key q-chunk.
__global__ __launch_bounds__(256) void k_rankp(const float* __restrict__ sJ,
                                               int* __restrict__ rankPart){
  const int blk = blockIdx.x;
  const int jc = blk & 7;
  const int qc = (blk >> 3) & 7;
  const int b  = blk >> 6;
  __shared__ float v[256];
  const int t = threadIdx.x;
  const int qbase = qc * 256;
  v[t] = sJ[b * NN + qbase + t];
  const int j = jc * 256 + t;
  const float x = sJ[b * NN + j];
  __syncthreads();
  int r = 0;
  #pragma unroll 4
  for (int q4 = 0; q4 < 64; q4++){
    const int q = q4 * 4;
    float4 y = *(const float4*)&v[q];
    r += (y.x < x) || (y.x == x && (qbase + q + 0) < j);
    r += (y.y < x) || (y.y == x && (qbase + q + 1) < j);
    r += (y.z < x) || (y.z == x && (qbase + q + 2) < j);
    r += (y.w < x) || (y.w == x && (qbase + q + 3) < j);
  }
  rankPart[((size_t)(b * 8 + qc)) * NN + j] = r;
}

// ---------------- K2b: combine partials, scatter sorted arrays ----------------
__global__ __launch_bounds__(256) void k_scatter(const float* __restrict__ sJ,
                                                 const int* __restrict__ rankPart,
                                                 float* __restrict__ sortedS,
                                                 int* __restrict__ perm,
                                                 float* __restrict__ e1g,
                                                 float* __restrict__ e2g){
  const int b = blockIdx.x >> 3;
  const int jc = blockIdx.x & 7;
  const int j = jc * 256 + threadIdx.x;
  int r = 0;
  #pragma unroll
  for (int qc = 0; qc < 8; qc++)
    r += rankPart[((size_t)(b * 8 + qc)) * NN + j];
  const float x = sJ[b * NN + j];
  sortedS[b * NN + r] = x;
  perm[b * NN + r] = j;
  e1g[b * NN + r] = expf(x);
  e2g[b * NN + r] = expf(0.01f * x);
}

// ---------------- K3: scalar inclusive prefix sums of e1, e2 (green) ----------------
__global__ __launch_bounds__(256) void k_sscan(const float* __restrict__ e1g,
                                               const float* __restrict__ e2g,
                                               float* __restrict__ aPre,
                                               float* __restrict__ bPre){
  const int b = blockIdx.x;
  const int t = threadIdx.x;
  __shared__ float p1[256], p2[256];
  __shared__ float x1[256], x2[256];
  const float* e1 = e1g + b * NN;
  const float* e2 = e2g + b * NN;
  float l1[8], l2[8];
  float s1 = 0.f, s2 = 0.f;
  #pragma unroll
  for (int q = 0; q < 8; q++){
    s1 += e1[t * 8 + q]; l1[q] = s1;
    s2 += e2[t * 8 + q]; l2[q] = s2;
  }
  p1[t] = s1; p2[t] = s2;
  __syncthreads();
  if (t == 0){
    float a = 0.f, c = 0.f;
    for (int q = 0; q < 256; q++){
      x1[q] = a; a += p1[q];
      x2[q] = c; c += p2[q];
    }
  }
  __syncthreads();
  const float b1 = x1[t], b2 = x2[t];
  float* aP = aPre + b * NP1;
  float* bP = bPre + b * NP1;
  #pragma unroll
  for (int q = 0; q < 8; q++){
    aP[1 + t * 8 + q] = b1 + l1[q];
    bP[1 + t * 8 + q] = b2 + l2[q];
  }
  if (t == 0){ aP[0] = 0.f; bP[0] = 0.f; }
}

// ---------------- K4a: per-chunk vector totals (green) ----------------
__global__ __launch_bounds__(128) void k_csum(const float* __restrict__ Wh,
                                              const int* __restrict__ perm,
                                              const float* __restrict__ e1g,
                                              const float* __restrict__ e2g,
                                              float* __restrict__ T1,
                                              float* __restrict__ T2){
  const int b = blockIdx.x >> 6;
  const int c = blockIdx.x & 63;
  const int o = threadIdx.x;
  const int* pm = perm + b * NN + c * CLEN;
  const float* e1 = e1g + b * NN + c * CLEN;
  const float* e2 = e2g + b * NN + c * CLEN;
  const float* whb = Wh + (size_t)b * NN * FOUT;
  float t1 = 0.f, t2 = 0.f;
  #pragma unroll 8
  for (int r = 0; r < CLEN; r++){
    float w = whb[(size_t)pm[r] * FOUT + o];
    t1 = fmaf(e1[r], w, t1);
    t2 = fmaf(e2[r], w, t2);
  }
  T1[(size_t)(b * CHK + c) * FOUT + o] = t1;
  T2[(size_t)(b * CHK + c) * FOUT + o] = t2;
}

// ---------------- K4b: chunk-offset + local scan (green) ----------------
__global__ __launch_bounds__(128) void k_scan2(const float* __restrict__ Wh,
                                               const int* __restrict__ perm,
                                               const float* __restrict__ e1g,
                                               const float* __restrict__ e2g,
                                               const float* __restrict__ T1,
                                               const float* __restrict__ T2,
                                               float* __restrict__ P1,
                                               float* __restrict__ P2){
  const int b = blockIdx.x >> 6;
  const int c = blockIdx.x & 63;
  const int o = threadIdx.x;
  float acc1 = 0.f, acc2 = 0.f;
  for (int q = 0; q < c; q++){
    acc1 += T1[(size_t)(b * CHK + q) * FOUT + o];
    acc2 += T2[(size_t)(b * CHK + q) * FOUT + o];
  }
  const int g0 = c * CLEN;
  const int* pm = perm + b * NN + g0;
  const float* e1 = e1g + b * NN + g0;
  const float* e2 = e2g + b * NN + g0;
  const float* whb = Wh + (size_t)b * NN * FOUT;
  float* p1 = P1 + (size_t)b * NP1 * FOUT + o;
  float* p2 = P2 + (size_t)b * NP1 * FOUT + o;
  if (c == 0){ p1[0] = 0.f; p2[0] = 0.f; }
  #pragma unroll 4
  for (int r = 0; r < CLEN; r++){
    float w = whb[(size_t)pm[r] * FOUT + o];
    acc1 = fmaf(e1[r], w, acc1);
    acc2 = fmaf(e2[r], w, acc2);
    p1[(size_t)(g0 + r + 1) * FOUT] = acc1;
    p2[(size_t)(g0 + r + 1) * FOUT] = acc2;
  }
}

// ---------------- K5: per-row combine, fp32 store (green) ----------------
__global__ __launch_bounds__(128) void k_out(const float* __restrict__ sI,
                                             const float* __restrict__ sortedS,
                                             const float* __restrict__ aPre,
                                             const float* __restrict__ bPre,
                                             const float* __restrict__ P1,
                                             const float* __restrict__ P2,
                                             float* __restrict__ out){
  const int row = blockIdx.x;
  const int b = row >> 11;
  const float s = sI[row];
  const float key = -s;
  const float* ss = sortedS + b * NN;
  int lo = 0, hi = NN;
  while (lo < hi){
    int mid = (lo + hi) >> 1;
    if (ss[mid] <= key) lo = mid + 1; else hi = mid;
  }
  const int k = lo;
  const float w1 = expf(s), w2 = expf(0.01f * s);
  const float aT = aPre[b * NP1 + NN];
  const float ak = aPre[b * NP1 + k];
  const float bk = bPre[b * NP1 + k];
  const float inv = 1.0f / (w1 * (aT - ak) + w2 * bk);
  const int o = threadIdx.x;
  const float* p1k = P1 + ((size_t)b * NP1 + k) * FOUT;
  const float* p1T = P1 + ((size_t)b * NP1 + NN) * FOUT;
  const float* p2k = P2 + ((size_t)b * NP1 + k) * FOUT;
  float num = w1 * (p1T[o] - p1k[o]) + w2 * p2k[o];
  out[(size_t)row * FOUT + o] = num * inv;
}

extern "C" void kernel_launch(void* const* d_in, const int* in_sizes, int n_in,
                              void* d_out, int out_size, void* d_ws, size_t ws_size,
                              hipStream_t stream){
  const float* h  = (const float*)d_in[0];
  const float* W  = (const float*)d_in[1];
  const float* ai = (const float*)d_in[2];
  const float* aj = (const float*)d_in[3];
  float* out = (float*)d_out;

  char* ws = (char*)d_ws;
  size_t off = 0;
  auto alloc = [&](size_t bytes) -> void* {
    void* p = ws + off;
    off += (bytes + 255) & ~(size_t)255;
    return p;
  };
  float* Wh       = (float*)alloc((size_t)ROWS * FOUT * 4);        // 8 MB
  float* sI       = (float*)alloc((size_t)ROWS * 4);
  float* sJ       = (float*)alloc((size_t)ROWS * 4);
  float* sortedS  = (float*)alloc((size_t)BATCH * NN * 4);
  int*   perm     = (int*)  alloc((size_t)BATCH * NN * 4);
  float* e1       = (float*)alloc((size_t)BATCH * NN * 4);
  float* e2       = (float*)alloc((size_t)BATCH * NN * 4);
  float* aPre     = (float*)alloc((size_t)BATCH * NP1 * 4);
  float* bPre     = (float*)alloc((size_t)BATCH * NP1 * 4);
  int*   rankPart = (int*)  alloc((size_t)BATCH * 8 * NN * 4);     // 512 KB
  float* T1       = (float*)alloc((size_t)BATCH * CHK * FOUT * 4); // 256 KB
  float* T2       = (float*)alloc((size_t)BATCH * CHK * FOUT * 4); // 256 KB
  float* P1       = (float*)alloc((size_t)BATCH * NP1 * FOUT * 4); // 8.4 MB
  float* P2       = (float*)alloc((size_t)BATCH * NP1 * FOUT * 4); // 8.4 MB

  k_gemm   <<<ROWS / 32, 256, 0, stream>>>(h, W, ai, aj, Wh, sI, sJ);
  k_rankp  <<<BATCH * 64, 256, 0, stream>>>(sJ, rankPart);
  k_scatter<<<BATCH * 8, 256, 0, stream>>>(sJ, rankPart, sortedS, perm, e1, e2);
  k_sscan  <<<BATCH, 256, 0, stream>>>(e1, e2, aPre, bPre);
  k_csum   <<<BATCH * CHK, 128, 0, stream>>>(Wh, perm, e1, e2, T1, T2);
  k_scan2  <<<BATCH * CHK, 128, 0, stream>>>(Wh, perm, e1, e2, T1, T2, P1, P2);
  k_out    <<<ROWS, 128, 0, stream>>>(sI, sortedS, aPre, bPre, P1, P2, out);
}

// Round 14
// 143.021 us; speedup vs baseline: 3.0050x; 1.0266x over previous
//
#include <hip/hip_runtime.h>
#include <hip/hip_bf16.h>

#define BATCH 8
#define NN 2048
#define FIN 256
#define FOUT 128
#define ROWS (BATCH*NN)
#define NP1 (NN+1)
#define CHK 64           // chunks per batch (vector scan)
#define CLEN (NN/CHK)    // 32 rows per chunk

__device__ __forceinline__ unsigned pack2(float a, float b){
  __hip_bfloat16 x = __float2bfloat16(a), y = __float2bfloat16(b);
  unsigned short ux = *(unsigned short*)&x, uy = *(unsigned short*)&y;
  return ((unsigned)uy << 16) | (unsigned)ux;
}
__device__ __forceinline__ float lo2f(unsigned u){ union{unsigned v;float f;}c; c.v = u << 16; return c.f; }
__device__ __forceinline__ float hi2f(unsigned u){ union{unsigned v;float f;}c; c.v = u & 0xffff0000u; return c.f; }

// ---------------- K1: tiled Wh = h @ W + fused s_i/s_j ----------------
// 32x128 tile, BK=32; As stored TRANSPOSED [k][m] so the A-fragment is one
// broadcast ds_read_b128 (was 4 scalar reads) -> VALU-bound inner loop.
__global__ __launch_bounds__(256) void k_gemm(const float* __restrict__ h,
                                              const float* __restrict__ W,
                                              const float* __restrict__ ai,
                                              const float* __restrict__ aj,
                                              float* __restrict__ Wh,
                                              float* __restrict__ sI,
                                              float* __restrict__ sJ){
  __shared__ float As[32][36];    // [k][m], pad 36 (16B-aligned rows)
  __shared__ float Bs[32][128];   // [k][o]
  const int t = threadIdx.x;
  const int rbase = blockIdx.x * 32;
  const int tx = t & 31, ty = t >> 5;
  const int o0 = tx * 4, m0 = ty * 4;
  const int ar = t >> 3, ak = (t & 7) * 4;
  float acc[4][4] = {};
  for (int k0 = 0; k0 < FIN; k0 += 32){
    {
      float4 hv = *(const float4*)&h[(size_t)(rbase + ar) * FIN + k0 + ak];
      As[ak + 0][ar] = hv.x; As[ak + 1][ar] = hv.y;
      As[ak + 2][ar] = hv.z; As[ak + 3][ar] = hv.w;
    }
    #pragma unroll
    for (int u = 0; u < 4; u++){
      int idx = t + u * 256;
      int kk = idx >> 5, q = idx & 31;
      *(float4*)&Bs[kk][q * 4] = *(const float4*)&W[(size_t)(k0 + kk) * FOUT + q * 4];
    }
    __syncthreads();
    #pragma unroll
    for (int kk = 0; kk < 32; kk++){
      float4 a4 = *(const float4*)&As[kk][m0];   // broadcast b128
      float4 bv = *(const float4*)&Bs[kk][o0];   // stride-1 b128
      acc[0][0] = fmaf(a4.x, bv.x, acc[0][0]); acc[0][1] = fmaf(a4.x, bv.y, acc[0][1]);
      acc[0][2] = fmaf(a4.x, bv.z, acc[0][2]); acc[0][3] = fmaf(a4.x, bv.w, acc[0][3]);
      acc[1][0] = fmaf(a4.y, bv.x, acc[1][0]); acc[1][1] = fmaf(a4.y, bv.y, acc[1][1]);
      acc[1][2] = fmaf(a4.y, bv.z, acc[1][2]); acc[1][3] = fmaf(a4.y, bv.w, acc[1][3]);
      acc[2][0] = fmaf(a4.z, bv.x, acc[2][0]); acc[2][1] = fmaf(a4.z, bv.y, acc[2][1]);
      acc[2][2] = fmaf(a4.z, bv.z, acc[2][2]); acc[2][3] = fmaf(a4.z, bv.w, acc[2][3]);
      acc[3][0] = fmaf(a4.w, bv.x, acc[3][0]); acc[3][1] = fmaf(a4.w, bv.y, acc[3][1]);
      acc[3][2] = fmaf(a4.w, bv.z, acc[3][2]); acc[3][3] = fmaf(a4.w, bv.w, acc[3][3]);
    }
    __syncthreads();
  }
  const float4 av = *(const float4*)&ai[o0];
  const float4 bjv = *(const float4*)&aj[o0];
  #pragma unroll
  for (int i = 0; i < 4; i++){
    float4 v = {acc[i][0], acc[i][1], acc[i][2], acc[i][3]};
    *(float4*)&Wh[(size_t)(rbase + m0 + i) * FOUT + o0] = v;
    float pi = v.x * av.x + v.y * av.y + v.z * av.z + v.w * av.w;
    float pj = v.x * bjv.x + v.y * bjv.y + v.z * bjv.z + v.w * bjv.w;
    #pragma unroll
    for (int m = 1; m < 32; m <<= 1){
      pi += __shfl_xor(pi, m);
      pj += __shfl_xor(pj, m);
    }
    if (tx == 0){
      sI[rbase + m0 + i] = pi;
      sJ[rbase + m0 + i] = pj;
    }
  }
}

// ---------------- K2a: partial rank counts, q-parallel (green R13) ----------------
__global__ __launch_bounds__(256) void k_rankp(const float* __restrict__ sJ,
                                               int* __restrict__ rankPart){
  const int blk = blockIdx.x;
  const int jc = blk & 7;
  const int qc = (blk >> 3) & 7;
  const int b  = blk >> 6;
  __shared__ float v[256];
  const int t = threadIdx.x;
  const int qbase = qc * 256;
  v[t] = sJ[b * NN + qbase + t];
  const int j = jc * 256 + t;
  const float x = sJ[b * NN + j];
  __syncthreads();
  int r = 0;
  #pragma unroll 4
  for (int q4 = 0; q4 < 64; q4++){
    const int q = q4 * 4;
    float4 y = *(const float4*)&v[q];
    r += (y.x < x) || (y.x == x && (qbase + q + 0) < j);
    r += (y.y < x) || (y.y == x && (qbase + q + 1) < j);
    r += (y.z < x) || (y.z == x && (qbase + q + 2) < j);
    r += (y.w < x) || (y.w == x && (qbase + q + 3) < j);
  }
  rankPart[((size_t)(b * 8 + qc)) * NN + j] = r;
}

// ---------------- K2b: combine partials, scatter sorted arrays (green R13) ----------------
__global__ __launch_bounds__(256) void k_scatter(const float* __restrict__ sJ,
                                                 const int* __restrict__ rankPart,
                                                 float* __restrict__ sortedS,
                                                 int* __restrict__ perm,
                                                 float* __restrict__ e1g,
                                                 float* __restrict__ e2g){
  const int b = blockIdx.x >> 3;
  const int jc = blockIdx.x & 7;
  const int j = jc * 256 + threadIdx.x;
  int r = 0;
  #pragma unroll
  for (int qc = 0; qc < 8; qc++)
    r += rankPart[((size_t)(b * 8 + qc)) * NN + j];
  const float x = sJ[b * NN + j];
  sortedS[b * NN + r] = x;
  perm[b * NN + r] = j;
  e1g[b * NN + r] = expf(x);
  e2g[b * NN + r] = expf(0.01f * x);
}

// ---------------- K3: scalar inclusive prefix sums of e1, e2 (green) ----------------
__global__ __launch_bounds__(256) void k_sscan(const float* __restrict__ e1g,
                                               const float* __restrict__ e2g,
                                               float* __restrict__ aPre,
                                               float* __restrict__ bPre){
  const int b = blockIdx.x;
  const int t = threadIdx.x;
  __shared__ float p1[256], p2[256];
  __shared__ float x1[256], x2[256];
  const float* e1 = e1g + b * NN;
  const float* e2 = e2g + b * NN;
  float l1[8], l2[8];
  float s1 = 0.f, s2 = 0.f;
  #pragma unroll
  for (int q = 0; q < 8; q++){
    s1 += e1[t * 8 + q]; l1[q] = s1;
    s2 += e2[t * 8 + q]; l2[q] = s2;
  }
  p1[t] = s1; p2[t] = s2;
  __syncthreads();
  if (t == 0){
    float a = 0.f, c = 0.f;
    for (int q = 0; q < 256; q++){
      x1[q] = a; a += p1[q];
      x2[q] = c; c += p2[q];
    }
  }
  __syncthreads();
  const float b1 = x1[t], b2 = x2[t];
  float* aP = aPre + b * NP1;
  float* bP = bPre + b * NP1;
  #pragma unroll
  for (int q = 0; q < 8; q++){
    aP[1 + t * 8 + q] = b1 + l1[q];
    bP[1 + t * 8 + q] = b2 + l2[q];
  }
  if (t == 0){ aP[0] = 0.f; bP[0] = 0.f; }
}

// ---------------- K4a: per-chunk vector totals (green) ----------------
__global__ __launch_bounds__(128) void k_csum(const float* __restrict__ Wh,
                                              const int* __restrict__ perm,
                                              const float* __restrict__ e1g,
                                              const float* __restrict__ e2g,
                                              float* __restrict__ T1,
                                              float* __restrict__ T2){
  const int b = blockIdx.x >> 6;
  const int c = blockIdx.x & 63;
  const int o = threadIdx.x;
  const int* pm = perm + b * NN + c * CLEN;
  const float* e1 = e1g + b * NN + c * CLEN;
  const float* e2 = e2g + b * NN + c * CLEN;
  const float* whb = Wh + (size_t)b * NN * FOUT;
  float t1 = 0.f, t2 = 0.f;
  #pragma unroll 8
  for (int r = 0; r < CLEN; r++){
    float w = whb[(size_t)pm[r] * FOUT + o];
    t1 = fmaf(e1[r], w, t1);
    t2 = fmaf(e2[r], w, t2);
  }
  T1[(size_t)(b * CHK + c) * FOUT + o] = t1;
  T2[(size_t)(b * CHK + c) * FOUT + o] = t2;
}

// ---------------- K4b: chunk-offset + local scan -> PACKED bf16x2 P ----------------
__global__ __launch_bounds__(128) void k_scan2(const float* __restrict__ Wh,
                                               const int* __restrict__ perm,
                                               const float* __restrict__ e1g,
                                               const float* __restrict__ e2g,
                                               const float* __restrict__ T1,
                                               const float* __restrict__ T2,
                                               unsigned* __restrict__ P12){
  const int b = blockIdx.x >> 6;
  const int c = blockIdx.x & 63;
  const int o = threadIdx.x;
  float acc1 = 0.f, acc2 = 0.f;
  for (int q = 0; q < c; q++){
    acc1 += T1[(size_t)(b * CHK + q) * FOUT + o];
    acc2 += T2[(size_t)(b * CHK + q) * FOUT + o];
  }
  const int g0 = c * CLEN;
  const int* pm = perm + b * NN + g0;
  const float* e1 = e1g + b * NN + g0;
  const float* e2 = e2g + b * NN + g0;
  const float* whb = Wh + (size_t)b * NN * FOUT;
  unsigned* p = P12 + (size_t)b * NP1 * FOUT + o;
  if (c == 0) p[0] = 0u;
  #pragma unroll 4
  for (int r = 0; r < CLEN; r++){
    float w = whb[(size_t)pm[r] * FOUT + o];
    acc1 = fmaf(e1[r], w, acc1);
    acc2 = fmaf(e2[r], w, acc2);
    p[(size_t)(g0 + r + 1) * FOUT] = pack2(acc1, acc2);
  }
}

// ---------------- K5: per-row combine, fp32 store (packed P reads) ----------------
__global__ __launch_bounds__(128) void k_out(const float* __restrict__ sI,
                                             const float* __restrict__ sortedS,
                                             const float* __restrict__ aPre,
                                             const float* __restrict__ bPre,
                                             const unsigned* __restrict__ P12,
                                             float* __restrict__ out){
  const int row = blockIdx.x;
  const int b = row >> 11;
  const float s = sI[row];
  const float key = -s;
  const float* ss = sortedS + b * NN;
  int lo = 0, hi = NN;
  while (lo < hi){
    int mid = (lo + hi) >> 1;
    if (ss[mid] <= key) lo = mid + 1; else hi = mid;
  }
  const int k = lo;
  const float w1 = expf(s), w2 = expf(0.01f * s);
  const float aT = aPre[b * NP1 + NN];
  const float ak = aPre[b * NP1 + k];
  const float bk = bPre[b * NP1 + k];
  const float inv = 1.0f / (w1 * (aT - ak) + w2 * bk);
  const int o = threadIdx.x;
  const unsigned uk = P12[((size_t)b * NP1 + k) * FOUT + o];
  const unsigned uT = P12[((size_t)b * NP1 + NN) * FOUT + o];
  float num = w1 * (lo2f(uT) - lo2f(uk)) + w2 * hi2f(uk);
  out[(size_t)row * FOUT + o] = num * inv;
}

extern "C" void kernel_launch(void* const* d_in, const int* in_sizes, int n_in,
                              void* d_out, int out_size, void* d_ws, size_t ws_size,
                              hipStream_t stream){
  const float* h  = (const float*)d_in[0];
  const float* W  = (const float*)d_in[1];
  const float* ai = (const float*)d_in[2];
  const float* aj = (const float*)d_in[3];
  float* out = (float*)d_out;

  char* ws = (char*)d_ws;
  size_t off = 0;
  auto alloc = [&](size_t bytes) -> void* {
    void* p = ws + off;
    off += (bytes + 255) & ~(size_t)255;
    return p;
  };
  float*    Wh       = (float*)   alloc((size_t)ROWS * FOUT * 4);        // 8 MB
  float*    sI       = (float*)   alloc((size_t)ROWS * 4);
  float*    sJ       = (float*)   alloc((size_t)ROWS * 4);
  float*    sortedS  = (float*)   alloc((size_t)BATCH * NN * 4);
  int*      perm     = (int*)     alloc((size_t)BATCH * NN * 4);
  float*    e1       = (float*)   alloc((size_t)BATCH * NN * 4);
  float*    e2       = (float*)   alloc((size_t)BATCH * NN * 4);
  float*    aPre     = (float*)   alloc((size_t)BATCH * NP1 * 4);
  float*    bPre     = (float*)   alloc((size_t)BATCH * NP1 * 4);
  int*      rankPart = (int*)     alloc((size_t)BATCH * 8 * NN * 4);     // 512 KB
  float*    T1       = (float*)   alloc((size_t)BATCH * CHK * FOUT * 4); // 256 KB
  float*    T2       = (float*)   alloc((size_t)BATCH * CHK * FOUT * 4); // 256 KB
  unsigned* P12      = (unsigned*)alloc((size_t)BATCH * NP1 * FOUT * 4); // 8.4 MB

  k_gemm   <<<ROWS / 32, 256, 0, stream>>>(h, W, ai, aj, Wh, sI, sJ);
  k_rankp  <<<BATCH * 64, 256, 0, stream>>>(sJ, rankPart);
  k_scatter<<<BATCH * 8, 256, 0, stream>>>(sJ, rankPart, sortedS, perm, e1, e2);
  k_sscan  <<<BATCH, 256, 0, stream>>>(e1, e2, aPre, bPre);
  k_csum   <<<BATCH * CHK, 128, 0, stream>>>(Wh, perm, e1, e2, T1, T2);
  k_scan2  <<<BATCH * CHK, 128, 0, stream>>>(Wh, perm, e1, e2, T1, T2, P12);
  k_out    <<<ROWS, 128, 0, stream>>>(sI, sortedS, aPre, bPre, P12, out);
}